// Round 1
// baseline (4901.425 us; speedup 1.0000x reference)
//
#include <hip/hip_runtime.h>
#include <hip/hip_bf16.h>

// Problem constants
#define T_STEPS 8
#define BATCH 32
#define RR 56            // C*Tp = 4*14
#define MROWS (BATCH*RR) // 1792
#define H0 2048
#define H1 2048
#define H2 1024
#define D_IN 1024
#define F_OUT (RR*H2)    // 57344

// ---------------- Pool: x[32,4,232,64,64] -> feat[8,32,56,1024] ----------------
__global__ __launch_bounds__(256) void pool_kernel(const float* __restrict__ x,
                                                   float* __restrict__ feat) {
    int tid = blockIdx.x * 256 + threadIdx.x;
    const int total = T_STEPS * BATCH * RR * 1024; // 14,680,064
    if (tid >= total) return;
    int d    = tid & 1023;
    int rest = tid >> 10;
    int r  = rest % RR;
    int tb = rest / RR;
    int b  = tb & 31;
    int t  = tb >> 5;
    int c  = r / 14, tp = r % 14;
    int hp = d >> 5, wp = d & 31;
    int n0 = t * 29 + 2 * tp;
    const float* xp = x + (((size_t)(b * 4 + c) * 232 + n0) * 4096) + (hp * 2) * 64 + (wp * 2);
    float s = 0.f;
    #pragma unroll
    for (int kd = 0; kd < 3; ++kd) {
        const float* xq = xp + (size_t)kd * 4096;
        s += xq[0] + xq[1] + xq[64] + xq[65];
    }
    feat[tid] = s / 12.0f;
}

// ---------------- fp32 GEMM (64x64x16 tile) + fused LIF epilogue ----------------
// C = A[M,K] @ B[K,N] + bias;  LIF: reset=(mem>thr)?thr:0; mem=beta*mem+cur-reset;
// spk=(mem-thr>0)?1:0.  Each output element owned by exactly one thread.
#define BM 64
#define BN 64
#define BK 16
__global__ __launch_bounds__(256) void gemm_lif(
    const float* __restrict__ A, const float* __restrict__ B,
    const float* __restrict__ bias, float* __restrict__ mem,
    float* __restrict__ spk, int M, int N, int K,
    const float* __restrict__ betas, int bi,
    const float* __restrict__ thrs, int ti)
{
    __shared__ float As[BK][BM];
    __shared__ float Bs[BK][BN];
    const int tid = threadIdx.x;
    const int tx = tid & 15, ty = tid >> 4;
    const int row0 = blockIdx.y * BM, col0 = blockIdx.x * BN;

    const int arow = tid >> 2;          // 0..63
    const int acol = (tid & 3) * 4;     // 0,4,8,12
    const int brow = tid >> 4;          // 0..15
    const int bcol = (tid & 15) * 4;    // 0..60

    float acc[4][4] = {};

    for (int k0 = 0; k0 < K; k0 += BK) {
        float4 av = *(const float4*)(A + (size_t)(row0 + arow) * K + k0 + acol);
        float4 bv = *(const float4*)(B + (size_t)(k0 + brow) * N + col0 + bcol);
        As[acol + 0][arow] = av.x;
        As[acol + 1][arow] = av.y;
        As[acol + 2][arow] = av.z;
        As[acol + 3][arow] = av.w;
        *(float4*)&Bs[brow][bcol] = bv;
        __syncthreads();
        #pragma unroll
        for (int k = 0; k < BK; ++k) {
            float am[4], bn[4];
            *(float4*)am = *(const float4*)&As[k][ty * 4];
            *(float4*)bn = *(const float4*)&Bs[k][tx * 4];
            #pragma unroll
            for (int i = 0; i < 4; ++i)
                #pragma unroll
                for (int j = 0; j < 4; ++j)
                    acc[i][j] += am[i] * bn[j];
        }
        __syncthreads();
    }

    float beta = betas[bi];
    beta = fminf(fmaxf(beta, 0.0f), 1.0f);
    const float thr = thrs[ti];

    #pragma unroll
    for (int i = 0; i < 4; ++i) {
        int m = row0 + ty * 4 + i;
        #pragma unroll
        for (int j = 0; j < 4; ++j) {
            int n = col0 + tx * 4 + j;
            float cur = acc[i][j] + bias[n];
            size_t idx = (size_t)m * N + n;
            float mold = mem[idx];
            float reset = (mold > thr) ? thr : 0.0f;
            float mnew = beta * mold + cur - reset;
            mem[idx] = mnew;
            spk[idx] = (mnew - thr > 0.0f) ? 1.0f : 0.0f;
        }
    }
}

// ---------------- Readout: cur_out[b,j] = spk2[b,:] . W_out[:,j] + b_out, LIF(thr=1) ----------------
__global__ __launch_bounds__(256) void out_step(
    const float* __restrict__ spk2, const float* __restrict__ W_out,
    const float* __restrict__ b_out, float* __restrict__ m_out,
    float* __restrict__ out, const float* __restrict__ betas, int t)
{
    const int b = blockIdx.x;
    const int tid = threadIdx.x;
    const float* s = spk2 + (size_t)b * F_OUT;
    double a0 = 0, a1 = 0, a2 = 0, a3 = 0;
    for (int i = tid; i < F_OUT; i += 256) {
        float sv = s[i];
        const float4 w = *(const float4*)(W_out + (size_t)i * 4);
        a0 += (double)(sv * w.x);
        a1 += (double)(sv * w.y);
        a2 += (double)(sv * w.z);
        a3 += (double)(sv * w.w);
    }
    __shared__ double red[256][4];
    red[tid][0] = a0; red[tid][1] = a1; red[tid][2] = a2; red[tid][3] = a3;
    __syncthreads();
    for (int s2 = 128; s2 > 0; s2 >>= 1) {
        if (tid < s2) {
            red[tid][0] += red[tid + s2][0];
            red[tid][1] += red[tid + s2][1];
            red[tid][2] += red[tid + s2][2];
            red[tid][3] += red[tid + s2][3];
        }
        __syncthreads();
    }
    if (tid < 4) {
        float beta = betas[3];
        beta = fminf(fmaxf(beta, 0.0f), 1.0f);
        float cur = (float)red[0][tid] + b_out[tid];
        float mold = m_out[b * 4 + tid];
        float reset = (mold > 1.0f) ? 1.0f : 0.0f;
        float mnew = beta * mold + cur - reset;
        m_out[b * 4 + tid] = mnew;
        out[((size_t)t * BATCH + b) * 4 + tid] = (mnew - 1.0f > 0.0f) ? 1.0f : 0.0f;
    }
}

extern "C" void kernel_launch(void* const* d_in, const int* in_sizes, int n_in,
                              void* d_out, int out_size, void* d_ws, size_t ws_size,
                              hipStream_t stream) {
    const float* x     = (const float*)d_in[0];
    const float* W_in  = (const float*)d_in[1];
    const float* b_in  = (const float*)d_in[2];
    const float* W_h1  = (const float*)d_in[3];
    const float* b_h1  = (const float*)d_in[4];
    const float* W_h2  = (const float*)d_in[5];
    const float* b_h2  = (const float*)d_in[6];
    const float* W_out = (const float*)d_in[7];
    const float* b_out = (const float*)d_in[8];
    const float* betas = (const float*)d_in[9];
    const float* thrs  = (const float*)d_in[10];
    float* out = (float*)d_out;

    char* ws = (char*)d_ws;
    size_t off = 0;
    float* m_in  = (float*)(ws + off); off += (size_t)MROWS * H0 * 4;   // 14,680,064
    float* m_h1  = (float*)(ws + off); off += (size_t)MROWS * H1 * 4;   // 14,680,064
    float* m_h2  = (float*)(ws + off); off += (size_t)MROWS * H2 * 4;   //  7,340,032
    float* m_out = (float*)(ws + off); off += 512;                       // 32*4*4
    size_t zero_bytes = off;                                             // 36,700,672
    float* feat   = (float*)(ws + off); off += (size_t)T_STEPS * MROWS * D_IN * 4; // 58,720,256
    float* spk_in = (float*)(ws + off); off += (size_t)MROWS * H0 * 4;
    float* spk1   = (float*)(ws + off); off += (size_t)MROWS * H1 * 4;
    float* spk2   = (float*)(ws + off); off += (size_t)MROWS * H2 * 4;

    // zero-init membrane state (ws is poisoned 0xAA before every launch)
    hipMemsetAsync(d_ws, 0, zero_bytes, stream);

    // pooling for all timesteps
    {
        const int total = T_STEPS * MROWS * D_IN;
        pool_kernel<<<(total + 255) / 256, 256, 0, stream>>>(x, feat);
    }

    for (int t = 0; t < T_STEPS; ++t) {
        const float* At = feat + (size_t)t * MROWS * D_IN;
        // fc_in + LIF0
        gemm_lif<<<dim3(H0 / BN, MROWS / BM), 256, 0, stream>>>(
            At, W_in, b_in, m_in, spk_in, MROWS, H0, D_IN, betas, 0, thrs, 0);
        // fc_h1 + LIF1
        gemm_lif<<<dim3(H1 / BN, MROWS / BM), 256, 0, stream>>>(
            spk_in, W_h1, b_h1, m_h1, spk1, MROWS, H1, H0, betas, 1, thrs, 1);
        // fc_h2 + LIF2
        gemm_lif<<<dim3(H2 / BN, MROWS / BM), 256, 0, stream>>>(
            spk1, W_h2, b_h2, m_h2, spk2, MROWS, H2, H1, betas, 2, thrs, 2);
        // readout + LIF out (thr=1.0), fp64 accumulate
        out_step<<<BATCH, 256, 0, stream>>>(spk2, W_out, b_out, m_out, out, betas, t);
    }
    (void)in_sizes; (void)n_in; (void)out_size; (void)ws_size;
}